// Round 6
// baseline (159.292 us; speedup 1.0000x reference)
//
#include <hip/hip_runtime.h>
#include <math.h>

#define B_SZ 256
#define N_SZ 1024
#define D_MODEL 128
#define NUM_CLASSES 32
#define BLOCKS_PER_BATCH 4

typedef float vfloat4 __attribute__((ext_vector_type(4)));

// exp(-ETA*d^2) = 2^(d^2 * -ETA*log2(e));  -4 * 1.4426950408889634
#define K_EXP (-5.770780163555854f)
// cos(pi*rc/RC) with v_cos (revolutions): arg = rc/(2*RC) = rc/12
#define K_COS (1.0f / 12.0f)

__device__ __forceinline__ void compute_prod(const float4 xv, float& r, int& c, float p[4]) {
    const float y00 = 0.28209479177387814f;  // 0.5/sqrt(pi)
    const float c1  = 0.48860251190291992f;  // sqrt(3/(4pi))
    float r2 = xv.x * xv.x + xv.y * xv.y + xv.z * xv.z;
    r = sqrtf(r2);
    c = (int)xv.w;
    float inv_r = (r > 0.0f) ? __builtin_amdgcn_rcpf(r) : 0.0f;
    float ux = xv.x * inv_r, uy = xv.y * inv_r, uz = xv.z * inv_r;
    float rc = fminf(r, 6.0f);
    float env = 0.5f * __builtin_amdgcn_cosf(rc * K_COS) + 0.5f;
    float d0 = 0.0f - r, d1 = 1.5f - r, d2 = 3.0f - r, d3 = 4.5f - r;
    float rad0 = __builtin_amdgcn_exp2f(d0 * d0 * K_EXP);
    float rad1 = __builtin_amdgcn_exp2f(d1 * d1 * K_EXP);
    float rad2 = __builtin_amdgcn_exp2f(d2 * d2 * K_EXP);
    float rad3 = __builtin_amdgcn_exp2f(d3 * d3 * K_EXP);
    p[0] = y00 * rad0 * env;
    p[1] = c1 * uy * rad1 * env;
    p[2] = c1 * uz * rad2 * env;
    p[3] = c1 * ux * rad3 * env;
}

// 4 blocks per batch (grid = 1024, 1024 threads). Each block redundantly runs
// phase 1 (full-batch reduction, 1 point/thread) then writes its quarter of
// the output. 2 blocks resident/CU -> one block's phase-1 latency overlaps
// another's phase-3 store stream.
__global__ __launch_bounds__(1024) void ape_fused_kernel(const float* __restrict__ x,
                                                         float* __restrict__ out) {
    __shared__ float nsq[D_MODEL];
    __shared__ float invn[D_MODEL];
    __shared__ float sp0[N_SZ], sp1[N_SZ], sp2[N_SZ], sp3[N_SZ];
    __shared__ int   scls[N_SZ];

    const int b = blockIdx.x >> 2;       // batch
    const int q = blockIdx.x & 3;        // quarter
    const int t = threadIdx.x;
    if (t < D_MODEL) nsq[t] = 0.0f;
    __syncthreads();

    // Phase 1: one point per thread, full batch (redundant across the 4 blocks)
    {
        float4 xv = ((const float4*)x)[(size_t)b * N_SZ + t];
        float r; int c; float p[4];
        compute_prod(xv, r, c, p);
        if (r <= 0.0f) { p[0] = p[1] = p[2] = p[3] = 0.0f; }
        sp0[t] = p[0]; sp1[t] = p[1]; sp2[t] = p[2]; sp3[t] = p[3];
        scls[t] = c;
        if (r > 0.0f) {
            atomicAdd(&nsq[0 * NUM_CLASSES + c], p[0] * p[0]);
            atomicAdd(&nsq[1 * NUM_CLASSES + c], p[1] * p[1]);
            atomicAdd(&nsq[2 * NUM_CLASSES + c], p[2] * p[2]);
            atomicAdd(&nsq[3 * NUM_CLASSES + c], p[3] * p[3]);
        }
    }
    __syncthreads();

    // Phase 2: inv_norm per feature
    if (t < D_MODEL) {
        invn[t] = __builtin_amdgcn_rcpf(fmaxf(sqrtf(nsq[t]), 1e-12f));
    }
    __syncthreads();

    // Phase 3: this block's quarter — 4 lanes per point, single pass.
    // Store j covers features [j*16 + sub*4, +4) at byte pt*512 + j*64 + sub*16,
    // so each wave store instruction writes 16 full 64B cachelines.
    const int sub = t & 3;
    const int hb = sub * 4;
    const int n = q * 256 + (t >> 2);
    const int c = scls[n];
    float pn0 = sp0[n] * invn[0 * NUM_CLASSES + c];
    float pn1 = sp1[n] * invn[1 * NUM_CLASSES + c];
    float pn2 = sp2[n] * invn[2 * NUM_CLASSES + c];
    float pn3 = sp3[n] * invn[3 * NUM_CLASSES + c];
    float sum = pn0 + pn1 + pn2 + pn3;
    float mean = sum * (1.0f / 128.0f);
    float sumsq = pn0 * pn0 + pn1 * pn1 + pn2 * pn2 + pn3 * pn3;
    float var = fmaxf((sumsq - 128.0f * mean * mean) * (1.0f / 127.0f), 0.0f);
    float inv_std = __builtin_amdgcn_rcpf(sqrtf(var) + 1e-6f);
    float bneg = -mean * inv_std;
    float amb[4];
    amb[0] = pn0 * inv_std + bneg;
    amb[1] = pn1 * inv_std + bneg;
    amb[2] = pn2 * inv_std + bneg;
    amb[3] = pn3 * inv_std + bneg;

    vfloat4* ob = (vfloat4*)out + ((size_t)b * N_SZ + n) * 32 + sub;
#pragma unroll
    for (int j = 0; j < 8; ++j) {
        const float a = amb[j >> 1];
        const int cb = (j & 1) * 16 + hb;
        vfloat4 o;
        o.x = (cb + 0 == c) ? a : bneg;
        o.y = (cb + 1 == c) ? a : bneg;
        o.z = (cb + 2 == c) ? a : bneg;
        o.w = (cb + 3 == c) ? a : bneg;
        __builtin_nontemporal_store(o, &ob[j * 4]);  // output never re-read
    }
}

extern "C" void kernel_launch(void* const* d_in, const int* in_sizes, int n_in,
                              void* d_out, int out_size, void* d_ws, size_t ws_size,
                              hipStream_t stream) {
    const float* x = (const float*)d_in[0];
    float* out = (float*)d_out;
    ape_fused_kernel<<<B_SZ * BLOCKS_PER_BATCH, 1024, 0, stream>>>(x, out);
}

// Round 7
// 140.681 us; speedup vs baseline: 1.1323x; 1.1323x over previous
//
#include <hip/hip_runtime.h>
#include <math.h>

#define B_SZ 256
#define N_SZ 1024
#define D_MODEL 128
#define NUM_CLASSES 32
#define BLOCKS_PER_BATCH 2

// exp(-ETA*d^2) = 2^(d^2 * -ETA*log2(e));  -4 * 1.4426950408889634
#define K_EXP (-5.770780163555854f)
// cos(pi*rc/RC) with v_cos (revolutions): arg = rc/(2*RC) = rc/12
#define K_COS (1.0f / 12.0f)

__device__ __forceinline__ void compute_prod(const float4 xv, float& r, int& c, float p[4]) {
    const float y00 = 0.28209479177387814f;  // 0.5/sqrt(pi)
    const float c1  = 0.48860251190291992f;  // sqrt(3/(4pi))
    float r2 = xv.x * xv.x + xv.y * xv.y + xv.z * xv.z;
    r = sqrtf(r2);
    c = (int)xv.w;
    float inv_r = (r > 0.0f) ? __builtin_amdgcn_rcpf(r) : 0.0f;
    float ux = xv.x * inv_r, uy = xv.y * inv_r, uz = xv.z * inv_r;
    float rc = fminf(r, 6.0f);
    float env = 0.5f * __builtin_amdgcn_cosf(rc * K_COS) + 0.5f;
    float d0 = 0.0f - r, d1 = 1.5f - r, d2 = 3.0f - r, d3 = 4.5f - r;
    float rad0 = __builtin_amdgcn_exp2f(d0 * d0 * K_EXP);
    float rad1 = __builtin_amdgcn_exp2f(d1 * d1 * K_EXP);
    float rad2 = __builtin_amdgcn_exp2f(d2 * d2 * K_EXP);
    float rad3 = __builtin_amdgcn_exp2f(d3 * d3 * K_EXP);
    p[0] = y00 * rad0 * env;
    p[1] = c1 * uy * rad1 * env;
    p[2] = c1 * uz * rad2 * env;
    p[3] = c1 * ux * rad3 * env;
}

// 2 blocks per batch (grid = 512, 1024 threads, forced <=64 VGPR so BOTH
// blocks are resident per CU: 32 waves = the CU max). Each block redundantly
// runs phase 1 (full-batch reduction) then writes its HALF of the output, so
// one block's phase-1 latency overlaps the other's phase-3 store stream.
__global__ __launch_bounds__(1024, 8) void ape_fused_kernel(const float* __restrict__ x,
                                                            float* __restrict__ out) {
    __shared__ float nsq[D_MODEL];
    __shared__ float invn[D_MODEL];
    __shared__ float sp0[N_SZ], sp1[N_SZ], sp2[N_SZ], sp3[N_SZ];
    __shared__ int   scls[N_SZ];

    const int b = blockIdx.x >> 1;       // batch
    const int q = blockIdx.x & 1;        // half
    const int t = threadIdx.x;
    if (t < D_MODEL) nsq[t] = 0.0f;
    __syncthreads();

    // Phase 1: one point per thread, full batch (redundant across the 2 blocks)
    {
        float4 xv = ((const float4*)x)[(size_t)b * N_SZ + t];
        float r; int c; float p[4];
        compute_prod(xv, r, c, p);
        if (r <= 0.0f) { p[0] = p[1] = p[2] = p[3] = 0.0f; }
        sp0[t] = p[0]; sp1[t] = p[1]; sp2[t] = p[2]; sp3[t] = p[3];
        scls[t] = c;
        if (r > 0.0f) {
            atomicAdd(&nsq[0 * NUM_CLASSES + c], p[0] * p[0]);
            atomicAdd(&nsq[1 * NUM_CLASSES + c], p[1] * p[1]);
            atomicAdd(&nsq[2 * NUM_CLASSES + c], p[2] * p[2]);
            atomicAdd(&nsq[3 * NUM_CLASSES + c], p[3] * p[3]);
        }
    }
    __syncthreads();

    // Phase 2: inv_norm per feature
    if (t < D_MODEL) {
        invn[t] = __builtin_amdgcn_rcpf(fmaxf(sqrtf(nsq[t]), 1e-12f));
    }
    __syncthreads();

    // Phase 3: this block's half — 4 lanes per point, 2 passes of 256 points.
    // Store j covers features [j*16 + sub*4, +4) at byte pt*512 + j*64 + sub*16,
    // so each wave store instruction writes 16 full 64B cachelines.
    const int sub = t & 3;
    const int hb = sub * 4;
#pragma unroll
    for (int k = 0; k < 2; ++k) {
        const int n = q * 512 + k * 256 + (t >> 2);
        const int c = scls[n];
        float pn0 = sp0[n] * invn[0 * NUM_CLASSES + c];
        float pn1 = sp1[n] * invn[1 * NUM_CLASSES + c];
        float pn2 = sp2[n] * invn[2 * NUM_CLASSES + c];
        float pn3 = sp3[n] * invn[3 * NUM_CLASSES + c];
        float sum = pn0 + pn1 + pn2 + pn3;
        float mean = sum * (1.0f / 128.0f);
        float sumsq = pn0 * pn0 + pn1 * pn1 + pn2 * pn2 + pn3 * pn3;
        float var = fmaxf((sumsq - 128.0f * mean * mean) * (1.0f / 127.0f), 0.0f);
        float inv_std = __builtin_amdgcn_rcpf(sqrtf(var) + 1e-6f);
        float bneg = -mean * inv_std;
        float amb[4];
        amb[0] = pn0 * inv_std + bneg;
        amb[1] = pn1 * inv_std + bneg;
        amb[2] = pn2 * inv_std + bneg;
        amb[3] = pn3 * inv_std + bneg;

        float4* ob = (float4*)out + ((size_t)b * N_SZ + n) * 32 + sub;
#pragma unroll
        for (int j = 0; j < 8; ++j) {
            const float a = amb[j >> 1];
            const int cb = (j & 1) * 16 + hb;
            float4 o;
            o.x = (cb + 0 == c) ? a : bneg;
            o.y = (cb + 1 == c) ? a : bneg;
            o.z = (cb + 2 == c) ? a : bneg;
            o.w = (cb + 3 == c) ? a : bneg;
            ob[j * 4] = o;
        }
    }
}

extern "C" void kernel_launch(void* const* d_in, const int* in_sizes, int n_in,
                              void* d_out, int out_size, void* d_ws, size_t ws_size,
                              hipStream_t stream) {
    const float* x = (const float*)d_in[0];
    float* out = (float*)d_out;
    ape_fused_kernel<<<B_SZ * BLOCKS_PER_BATCH, 1024, 0, stream>>>(x, out);
}